// Round 2
// baseline (418.528 us; speedup 1.0000x reference)
//
#include <hip/hip_runtime.h>
#include <hip/hip_bf16.h>

#define B_    64
#define T_    4096
#define DIM_  256
#define NLOC_ 32
#define KS_   31
#define PAD_  15
#define CHUNK_ 128
#define NCH_  (T_ / CHUNK_)   // 32 chunks per batch

typedef unsigned short u16;
typedef unsigned int   u32;

__device__ __forceinline__ float bf2f(u16 u) {
  return __uint_as_float(((u32)u) << 16);
}
__device__ __forceinline__ u16 f2bf(float f) {
  u32 x = __float_as_uint(f);
  return (u16)((x + 0x7fffu + ((x >> 16) & 1u)) >> 16);   // RNE
}

// dtype-generic scalar load
template<bool F32>
__device__ __forceinline__ float ldv(const void* p, size_t i) {
  if constexpr (F32) return ((const float*)p)[i];
  else               return bf2f(((const u16*)p)[i]);
}
// dtype-generic 8-element vector load (16B bf16 / 32B f32), 16B-aligned offs
template<bool F32>
__device__ __forceinline__ void ld8(const void* p, size_t i, float ef[8]) {
  if constexpr (F32) {
    const float4* q = (const float4*)((const float*)p + i);
    float4 a = q[0], b = q[1];
    ef[0]=a.x; ef[1]=a.y; ef[2]=a.z; ef[3]=a.w;
    ef[4]=b.x; ef[5]=b.y; ef[6]=b.z; ef[7]=b.w;
  } else {
    uint4 c = *(const uint4*)((const u16*)p + i);
    ef[0]=__uint_as_float(c.x << 16); ef[1]=__uint_as_float(c.x & 0xffff0000u);
    ef[2]=__uint_as_float(c.y << 16); ef[3]=__uint_as_float(c.y & 0xffff0000u);
    ef[4]=__uint_as_float(c.z << 16); ef[5]=__uint_as_float(c.z & 0xffff0000u);
    ef[6]=__uint_as_float(c.w << 16); ef[7]=__uint_as_float(c.w & 0xffff0000u);
  }
}

// -------- dtype probe: W_w as-bf16 extreme-value census ---------------------
// truly bf16 (values ~N(0,1/256)): ~0 extremes. f32 read as bf16: low halves
// have random exponents -> ~35% extremes over 4096 samples.
__global__ void k_detect(const u16* __restrict__ w, int* __restrict__ flag) {
  int tid = threadIdx.x;   // 64 threads
  int cnt = 0;
  for (int i = tid; i < 4096; i += 64) {
    float a = fabsf(bf2f(w[i]));
    if (!(a < 64.f) || (a > 0.f && a < 1e-20f)) cnt++;   // NaN lands here too
  }
  #pragma unroll
  for (int o = 32; o >= 1; o >>= 1) cnt += __shfl_xor(cnt, o, 64);
  if (tid == 0) *flag = (cnt > 200) ? 1 : 0;   // 1 => inputs are float32
}

// ---------------- Pass 0: fold query into W / (L_w, conv) ------------------
template<bool F32>
__device__ __forceinline__ void prep_body(
    const void* qv, const void* Ww, const void* Lw, const void* cw,
    const void* cb, float* qW, float* kern, float* bias)
{
  const int b = blockIdx.x, tid = threadIdx.x;
  __shared__ float q_s[DIM_];
  __shared__ float qL_s[NLOC_];
  q_s[tid] = ldv<F32>(qv, b * DIM_ + tid);
  __syncthreads();
  float acc = 0.f;
  #pragma unroll 8
  for (int e = 0; e < DIM_; ++e) acc += q_s[e] * ldv<F32>(Ww, e * DIM_ + tid);
  qW[b * DIM_ + tid] = acc;
  if (tid < NLOC_) {
    float a = 0.f;
    #pragma unroll 8
    for (int e = 0; e < DIM_; ++e) a += q_s[e] * ldv<F32>(Lw, e * NLOC_ + tid);
    qL_s[tid] = a;
  }
  __syncthreads();
  if (tid < KS_) {
    float a = 0.f;
    #pragma unroll
    for (int c = 0; c < NLOC_; ++c) a += ldv<F32>(cw, c * KS_ + tid) * qL_s[c];
    kern[b * 32 + tid] = a;
  } else if (tid == KS_) {
    float a = 0.f;
    #pragma unroll
    for (int c = 0; c < NLOC_; ++c) a += ldv<F32>(cb, c) * qL_s[c];
    bias[b] = a;
  }
}

__global__ __launch_bounds__(256) void k_prep(
    const void* qv, const void* Ww, const void* Lw, const void* cw,
    const void* cb, float* qW, float* kern, float* bias, const int* flag)
{
  if (*flag) prep_body<true >(qv, Ww, Lw, cw, cb, qW, kern, bias);
  else       prep_body<false>(qv, Ww, Lw, cw, cb, qW, kern, bias);
}

// ---------------- Pass 1: fused energies + online-softmax partials ----------
template<bool F32>
__device__ __forceinline__ void main_body(
    const void* enc, const void* mask,
    const float* qW, const float* kern, const float* bias,
    float* energies, float* blk_m, float* blk_Z, float* blk_ctx)
{
  const int b = blockIdx.y, ch = blockIdx.x, t0 = ch * CHUNK_;
  const int tid = threadIdx.x;
  const int wave = tid >> 6, lane = tid & 63, half = lane >> 5, hl = lane & 31;
  const int halfid = wave * 2 + half;

  __shared__ float mask_s[CHUNK_ + 2 * PAD_];
  __shared__ float kern_s[32];
  __shared__ float loc_s[CHUNK_];
  __shared__ float e_s[CHUNK_];
  __shared__ float pm[8], pZ[8];
  __shared__ float pctx[8][DIM_];

  for (int i = tid; i < CHUNK_ + 2 * PAD_; i += 256) {
    int g = t0 - PAD_ + i;
    mask_s[i] = (g >= 0 && g < T_) ? ldv<F32>(mask, (size_t)b * T_ + g) : 0.f;
  }
  if (tid < 32) kern_s[tid] = (tid < KS_) ? kern[b * 32 + tid] : bias[b];

  float wq[8];
  {
    const float4* q4 = (const float4*)(qW + b * DIM_ + 8 * hl);
    float4 a = q4[0], c = q4[1];
    wq[0]=a.x; wq[1]=a.y; wq[2]=a.z; wq[3]=a.w;
    wq[4]=c.x; wq[5]=c.y; wq[6]=c.z; wq[7]=c.w;
  }
  __syncthreads();

  if (tid < CHUNK_) {
    float a = kern_s[31];
    #pragma unroll
    for (int k = 0; k < KS_; ++k) a += mask_s[tid + k] * kern_s[k];
    loc_s[tid] = a;
  }
  __syncthreads();

  const int lbase = wave * (CHUNK_ / 4);
  const int tbase = t0 + lbase;
  float m = -INFINITY, Z = 0.f;
  float ctx[8];
  #pragma unroll
  for (int q = 0; q < 8; ++q) ctx[q] = 0.f;

  const size_t STEP = (size_t)2 * B_ * DIM_;
  const size_t base = (size_t)(tbase + half) * (B_ * DIM_) + b * DIM_ + 8 * hl;
  const int NIT = CHUNK_ / 8;  // 16

  auto process = [&](const float ef[8], int j) {
    float p = wq[0]*ef[0] + wq[1]*ef[1] + wq[2]*ef[2] + wq[3]*ef[3]
            + wq[4]*ef[4] + wq[5]*ef[5] + wq[6]*ef[6] + wq[7]*ef[7];
    #pragma unroll
    for (int o = 16; o >= 1; o >>= 1) p += __shfl_xor(p, o, 64);
    const int tloc = lbase + 2 * j + half;
    float e = p + loc_s[tloc];
    if (hl == 0) e_s[tloc] = e;
    float mn = fmaxf(m, e);
    float sc = __expf(m - mn);
    float w  = __expf(e - mn);
    Z = Z * sc + w;
    #pragma unroll
    for (int q = 0; q < 8; ++q) ctx[q] = ctx[q] * sc + w * ef[q];
    m = mn;
  };

  float efA[8], efB[8];
  ld8<F32>(enc, base, efA);
  #pragma unroll
  for (int j = 0; j < NIT; j += 2) {
    ld8<F32>(enc, base + (size_t)(j + 1) * STEP, efB);
    process(efA, j);
    if (j + 2 < NIT) ld8<F32>(enc, base + (size_t)(j + 2) * STEP, efA);
    process(efB, j + 1);
  }

  if (hl == 0) { pm[halfid] = m; pZ[halfid] = Z; }
  #pragma unroll
  for (int q = 0; q < 8; ++q) pctx[halfid][8 * hl + q] = ctx[q];
  __syncthreads();

  if (tid < CHUNK_) energies[(size_t)b * T_ + t0 + tid] = e_s[tid];

  float M = pm[0];
  #pragma unroll
  for (int i = 1; i < 8; ++i) M = fmaxf(M, pm[i]);
  float cx = 0.f;
  #pragma unroll
  for (int i = 0; i < 8; ++i) cx += __expf(pm[i] - M) * pctx[i][tid];
  blk_ctx[((size_t)b * NCH_ + ch) * DIM_ + tid] = cx;
  if (tid == 0) {
    float Zc = 0.f;
    #pragma unroll
    for (int i = 0; i < 8; ++i) Zc += __expf(pm[i] - M) * pZ[i];
    blk_m[b * NCH_ + ch] = M;
    blk_Z[b * NCH_ + ch] = Zc;
  }
}

__global__ __launch_bounds__(256) void k_main(
    const void* enc, const void* mask,
    const float* qW, const float* kern, const float* bias,
    float* energies, float* blk_m, float* blk_Z, float* blk_ctx,
    const int* flag)
{
  if (*flag) main_body<true >(enc, mask, qW, kern, bias, energies, blk_m, blk_Z, blk_ctx);
  else       main_body<false>(enc, mask, qW, kern, bias, energies, blk_m, blk_Z, blk_ctx);
}

// ---------------- Pass 2: combine chunk partials -> context + (M,Z) ---------
__global__ __launch_bounds__(256) void k_combine(
    const float* __restrict__ blk_m, const float* __restrict__ blk_Z,
    const float* __restrict__ blk_ctx,
    float* __restrict__ Mb, float* __restrict__ Zb, void* __restrict__ out,
    const int* __restrict__ flag)
{
  const int b = blockIdx.x, tid = threadIdx.x;
  __shared__ float sm[NCH_], sZ[NCH_];
  if (tid < NCH_) { sm[tid] = blk_m[b * NCH_ + tid]; sZ[tid] = blk_Z[b * NCH_ + tid]; }
  __syncthreads();
  float M = sm[0];
  #pragma unroll
  for (int i = 1; i < NCH_; ++i) M = fmaxf(M, sm[i]);
  float Zg = 0.f;
  #pragma unroll
  for (int i = 0; i < NCH_; ++i) Zg += __expf(sm[i] - M) * sZ[i];
  float cx = 0.f;
  for (int i = 0; i < NCH_; ++i)
    cx += __expf(sm[i] - M) * blk_ctx[((size_t)b * NCH_ + i) * DIM_ + tid];
  float v = cx / Zg;
  if (*flag) ((float*)out)[b * DIM_ + tid] = v;
  else       ((u16*)out)[b * DIM_ + tid]   = f2bf(v);
  if (tid == 0) { Mb[b] = M; Zb[b] = Zg; }
}

// ---------------- Pass 3: attn[b,t] = exp(e - M_b)/Z_b ----------------------
__global__ __launch_bounds__(256) void k_attn(
    const float* __restrict__ energies, const float* __restrict__ Mb,
    const float* __restrict__ Zb, void* __restrict__ out,
    const int* __restrict__ flag)
{
  const int idx = blockIdx.x * 256 + threadIdx.x;  // [0, B*T)
  const int b = idx >> 12;                          // T = 4096
  float a = __expf(energies[idx] - Mb[b]) / Zb[b];
  if (*flag) ((float*)out)[B_ * DIM_ + idx] = a;
  else       ((u16*)out)[B_ * DIM_ + idx]   = f2bf(a);
}

extern "C" void kernel_launch(void* const* d_in, const int* in_sizes, int n_in,
                              void* d_out, int out_size, void* d_ws, size_t ws_size,
                              hipStream_t stream) {
  const void* qv   = d_in[0];  // (1,64,256)
  const void* enc  = d_in[1];  // (4096,64,256)
  const void* mask = d_in[2];  // (64,4096,1)
  const void* Ww   = d_in[3];  // (256,256)
  const void* Lw   = d_in[4];  // (256,32)
  const void* cw   = d_in[5];  // (32,1,31)
  const void* cb   = d_in[6];  // (32,)

  float* ws     = (float*)d_ws;
  int*   flag   = (int*)ws;          // [0]
  float* qW     = ws + 64;           // 16384
  float* kern   = ws + 16448;        // 2048 (stride 32)
  float* bias   = ws + 18496;        // 64
  float* Mb     = ws + 18560;        // 64
  float* Zb     = ws + 18624;        // 64
  float* energ  = ws + 18688;        // 262144
  float* blk_m  = ws + 280832;       // 2048
  float* blk_Z  = ws + 282880;       // 2048
  float* blk_cx = ws + 284928;       // 524288  (total ~3.1 MiB)

  k_detect<<<1, 64, 0, stream>>>((const u16*)Ww, flag);
  k_prep<<<B_, 256, 0, stream>>>(qv, Ww, Lw, cw, cb, qW, kern, bias, flag);
  k_main<<<dim3(NCH_, B_), 256, 0, stream>>>(enc, mask, qW, kern, bias,
                                             energ, blk_m, blk_Z, blk_cx, flag);
  k_combine<<<B_, 256, 0, stream>>>(blk_m, blk_Z, blk_cx, Mb, Zb, d_out, flag);
  k_attn<<<(B_ * T_) / 256, 256, 0, stream>>>(energ, Mb, Zb, d_out, flag);
}

// Round 3
// 418.286 us; speedup vs baseline: 1.0006x; 1.0006x over previous
//
#include <hip/hip_runtime.h>
#include <hip/hip_bf16.h>

#define B_    64
#define T_    4096
#define DIM_  256
#define NLOC_ 32
#define KS_   31
#define PAD_  15
#define CHUNK_ 128
#define NCH_  (T_ / CHUNK_)   // 32 chunks per batch
#define HALO_ (CHUNK_ + 2 * PAD_)

typedef unsigned short u16;
typedef unsigned int   u32;

__device__ __forceinline__ float bf2f(u16 u) {
  return __uint_as_float(((u32)u) << 16);
}
__device__ __forceinline__ u16 f2bf(float f) {
  u32 x = __float_as_uint(f);
  return (u16)((x + 0x7fffu + ((x >> 16) & 1u)) >> 16);   // RNE
}

template<bool F32>
__device__ __forceinline__ float ldv(const void* p, size_t i) {
  if constexpr (F32) return ((const float*)p)[i];
  else               return bf2f(((const u16*)p)[i]);
}
template<bool F32>
__device__ __forceinline__ void ld8(const void* p, size_t i, float ef[8]) {
  if constexpr (F32) {
    const float4* q = (const float4*)((const float*)p + i);
    float4 a = q[0], b = q[1];
    ef[0]=a.x; ef[1]=a.y; ef[2]=a.z; ef[3]=a.w;
    ef[4]=b.x; ef[5]=b.y; ef[6]=b.z; ef[7]=b.w;
  } else {
    uint4 c = *(const uint4*)((const u16*)p + i);
    ef[0]=__uint_as_float(c.x << 16); ef[1]=__uint_as_float(c.x & 0xffff0000u);
    ef[2]=__uint_as_float(c.y << 16); ef[3]=__uint_as_float(c.y & 0xffff0000u);
    ef[4]=__uint_as_float(c.z << 16); ef[5]=__uint_as_float(c.z & 0xffff0000u);
    ef[6]=__uint_as_float(c.w << 16); ef[7]=__uint_as_float(c.w & 0xffff0000u);
  }
}

// -------- dtype probe (kept as insurance; R2 evidence says flag=0/bf16) -----
__global__ void k_detect(const u16* __restrict__ w, int* __restrict__ flag) {
  int tid = threadIdx.x;   // 64 threads
  int cnt = 0;
  for (int i = tid; i < 4096; i += 64) {
    float a = fabsf(bf2f(w[i]));
    if (!(a < 64.f) || (a > 0.f && a < 1e-20f)) cnt++;
  }
  #pragma unroll
  for (int o = 32; o >= 1; o >>= 1) cnt += __shfl_xor(cnt, o, 64);
  if (tid == 0) *flag = (cnt > 200) ? 1 : 0;
}

// ---------------- Pass 0: fold query into W / (L_w, conv) ------------------
template<bool F32>
__device__ __forceinline__ void prep_body(
    const void* qv, const void* Ww, const void* Lw, const void* cw,
    const void* cb, float* qW, float* kern, float* bias)
{
  const int b = blockIdx.x, tid = threadIdx.x;
  __shared__ float q_s[DIM_];
  __shared__ float qL_s[NLOC_];
  q_s[tid] = ldv<F32>(qv, b * DIM_ + tid);
  __syncthreads();
  float acc = 0.f;
  #pragma unroll 8
  for (int e = 0; e < DIM_; ++e) acc += q_s[e] * ldv<F32>(Ww, e * DIM_ + tid);
  qW[b * DIM_ + tid] = acc;
  if (tid < NLOC_) {
    float a = 0.f;
    #pragma unroll 8
    for (int e = 0; e < DIM_; ++e) a += q_s[e] * ldv<F32>(Lw, e * NLOC_ + tid);
    qL_s[tid] = a;
  }
  __syncthreads();
  if (tid < KS_) {
    float a = 0.f;
    #pragma unroll
    for (int c = 0; c < NLOC_; ++c) a += ldv<F32>(cw, c * KS_ + tid) * qL_s[c];
    kern[b * 32 + tid] = a;
  } else if (tid == KS_) {
    float a = 0.f;
    #pragma unroll
    for (int c = 0; c < NLOC_; ++c) a += ldv<F32>(cb, c) * qL_s[c];
    bias[b] = a;
  }
}

__global__ __launch_bounds__(256) void k_prep(
    const void* qv, const void* Ww, const void* Lw, const void* cw,
    const void* cb, float* qW, float* kern, float* bias, const int* flag)
{
  if (*flag) prep_body<true >(qv, Ww, Lw, cw, cb, qW, kern, bias);
  else       prep_body<false>(qv, Ww, Lw, cw, cb, qW, kern, bias);
}

// ---------------- Pass 1: fused energies + online-softmax partials ----------
// grid (NCH_, B_/2). Wave halves own adjacent batches (b0, b0+1) of the SAME
// t -> each wave load is one contiguous 1 KiB segment.
template<bool F32>
__device__ __forceinline__ void main_body(
    const void* enc, const void* mask,
    const float* qW, const float* kern, const float* bias,
    float* energies, float* blk_m, float* blk_Z, float* blk_ctx)
{
  const int ch = blockIdx.x, t0 = ch * CHUNK_;
  const int b0 = blockIdx.y * 2;
  const int tid = threadIdx.x;
  const int wave = tid >> 6, lane = tid & 63, half = lane >> 5, hl = lane & 31;
  const int b = b0 + half;
  const int halfid = wave * 2 + half;   // 0..7; parity = b offset

  __shared__ float mask_s[2][HALO_];
  __shared__ float kern_s[2][32];
  __shared__ float loc_s[2][CHUNK_];
  __shared__ float e_s[2][CHUNK_];
  __shared__ float pm[8], pZ[8];
  __shared__ float pctx[8][DIM_];

  for (int i = tid; i < 2 * HALO_; i += 256) {
    int bo = i / HALO_, ii = i - bo * HALO_;
    int g = t0 - PAD_ + ii;
    mask_s[bo][ii] = (g >= 0 && g < T_) ? ldv<F32>(mask, (size_t)(b0 + bo) * T_ + g) : 0.f;
  }
  if (tid < 64) {
    int bo = tid >> 5, k = tid & 31;
    kern_s[bo][k] = (k < KS_) ? kern[(b0 + bo) * 32 + k] : bias[b0 + bo];
  }

  float wq[8];
  {
    // contiguous across the wave: qW[b0*DIM + lane*8 .. +7]
    const float4* q4 = (const float4*)(qW + (size_t)b * DIM_ + 8 * hl);
    float4 a = q4[0], c = q4[1];
    wq[0]=a.x; wq[1]=a.y; wq[2]=a.z; wq[3]=a.w;
    wq[4]=c.x; wq[5]=c.y; wq[6]=c.z; wq[7]=c.w;
  }
  __syncthreads();

  {
    int bo = tid >> 7, i = tid & (CHUNK_ - 1);
    float a = kern_s[bo][31];
    #pragma unroll
    for (int k = 0; k < KS_; ++k) a += mask_s[bo][i + k] * kern_s[bo][k];
    loc_s[bo][i] = a;
  }
  __syncthreads();

  // wave covers t in [t0 + wave*32, +32), one t per iteration, both b's
  const int tA = t0 + wave * 32;
  float m = -INFINITY, Z = 0.f;
  float ctx[8];
  #pragma unroll
  for (int q = 0; q < 8; ++q) ctx[q] = 0.f;

  const size_t STEP = (size_t)B_ * DIM_;                  // one t row-block
  const size_t base = ((size_t)tA * B_ + b) * DIM_ + 8 * hl;
  const int NIT = 32;

  auto process = [&](const float ef[8], int j) {
    float p = wq[0]*ef[0] + wq[1]*ef[1] + wq[2]*ef[2] + wq[3]*ef[3]
            + wq[4]*ef[4] + wq[5]*ef[5] + wq[6]*ef[6] + wq[7]*ef[7];
    #pragma unroll
    for (int o = 16; o >= 1; o >>= 1) p += __shfl_xor(p, o, 64);
    const int tloc = wave * 32 + j;
    float e = p + loc_s[half][tloc];
    if (hl == 0) e_s[half][tloc] = e;
    float mn = fmaxf(m, e);
    float sc = __expf(m - mn);
    float w  = __expf(e - mn);
    Z = Z * sc + w;
    #pragma unroll
    for (int q = 0; q < 8; ++q) ctx[q] = ctx[q] * sc + w * ef[q];
    m = mn;
  };

  float efA[8], efB[8];
  ld8<F32>(enc, base, efA);
  for (int j = 0; j < NIT; j += 2) {
    ld8<F32>(enc, base + (size_t)(j + 1) * STEP, efB);
    process(efA, j);
    if (j + 2 < NIT) ld8<F32>(enc, base + (size_t)(j + 2) * STEP, efA);
    process(efB, j + 1);
  }

  if (hl == 0) { pm[halfid] = m; pZ[halfid] = Z; }
  #pragma unroll
  for (int q = 0; q < 8; ++q) pctx[halfid][8 * hl + q] = ctx[q];
  __syncthreads();

  // energies: 2 b's x 128 t
  {
    int bo = tid >> 7, i = tid & (CHUNK_ - 1);
    energies[(size_t)(b0 + bo) * T_ + t0 + i] = e_s[bo][i];
  }

  // combine the 4 wave-partials of each b
  #pragma unroll
  for (int bo = 0; bo < 2; ++bo) {
    float M = pm[bo];
    #pragma unroll
    for (int wv = 1; wv < 4; ++wv) M = fmaxf(M, pm[bo + 2 * wv]);
    float cx = 0.f;
    #pragma unroll
    for (int wv = 0; wv < 4; ++wv)
      cx += __expf(pm[bo + 2 * wv] - M) * pctx[bo + 2 * wv][tid];
    blk_ctx[((size_t)(b0 + bo) * NCH_ + ch) * DIM_ + tid] = cx;
    if (tid == 0) {
      float Zc = 0.f;
      #pragma unroll
      for (int wv = 0; wv < 4; ++wv) Zc += __expf(pm[bo + 2 * wv] - M) * pZ[bo + 2 * wv];
      blk_m[(b0 + bo) * NCH_ + ch] = M;
      blk_Z[(b0 + bo) * NCH_ + ch] = Zc;
    }
  }
}

__global__ __launch_bounds__(256) void k_main(
    const void* enc, const void* mask,
    const float* qW, const float* kern, const float* bias,
    float* energies, float* blk_m, float* blk_Z, float* blk_ctx,
    const int* flag)
{
  if (*flag) main_body<true >(enc, mask, qW, kern, bias, energies, blk_m, blk_Z, blk_ctx);
  else       main_body<false>(enc, mask, qW, kern, bias, energies, blk_m, blk_Z, blk_ctx);
}

// ---------------- Pass 2: combine chunk partials -> context + (M,Z) ---------
__global__ __launch_bounds__(256) void k_combine(
    const float* __restrict__ blk_m, const float* __restrict__ blk_Z,
    const float* __restrict__ blk_ctx,
    float* __restrict__ Mb, float* __restrict__ Zb, void* __restrict__ out,
    const int* __restrict__ flag)
{
  const int b = blockIdx.x, tid = threadIdx.x;
  __shared__ float sm[NCH_], sZ[NCH_];
  if (tid < NCH_) { sm[tid] = blk_m[b * NCH_ + tid]; sZ[tid] = blk_Z[b * NCH_ + tid]; }
  __syncthreads();
  float M = sm[0];
  #pragma unroll
  for (int i = 1; i < NCH_; ++i) M = fmaxf(M, sm[i]);
  float Zg = 0.f;
  #pragma unroll
  for (int i = 0; i < NCH_; ++i) Zg += __expf(sm[i] - M) * sZ[i];
  float cx = 0.f;
  for (int i = 0; i < NCH_; ++i)
    cx += __expf(sm[i] - M) * blk_ctx[((size_t)b * NCH_ + i) * DIM_ + tid];
  float v = cx / Zg;
  if (*flag) ((float*)out)[b * DIM_ + tid] = v;
  else       ((u16*)out)[b * DIM_ + tid]   = f2bf(v);
  if (tid == 0) { Mb[b] = M; Zb[b] = Zg; }
}

// ---------------- Pass 3: attn[b,t] = exp(e - M_b)/Z_b ----------------------
__global__ __launch_bounds__(256) void k_attn(
    const float* __restrict__ energies, const float* __restrict__ Mb,
    const float* __restrict__ Zb, void* __restrict__ out,
    const int* __restrict__ flag)
{
  const int idx = blockIdx.x * 256 + threadIdx.x;  // [0, B*T)
  const int b = idx >> 12;                          // T = 4096
  float a = __expf(energies[idx] - Mb[b]) / Zb[b];
  if (*flag) ((float*)out)[B_ * DIM_ + idx] = a;
  else       ((u16*)out)[B_ * DIM_ + idx]   = f2bf(a);
}

extern "C" void kernel_launch(void* const* d_in, const int* in_sizes, int n_in,
                              void* d_out, int out_size, void* d_ws, size_t ws_size,
                              hipStream_t stream) {
  const void* qv   = d_in[0];  // (1,64,256)
  const void* enc  = d_in[1];  // (4096,64,256)
  const void* mask = d_in[2];  // (64,4096,1)
  const void* Ww   = d_in[3];  // (256,256)
  const void* Lw   = d_in[4];  // (256,32)
  const void* cw   = d_in[5];  // (32,1,31)
  const void* cb   = d_in[6];  // (32,)

  float* ws     = (float*)d_ws;
  int*   flag   = (int*)ws;          // [0]
  float* qW     = ws + 64;           // 16384
  float* kern   = ws + 16448;        // 2048 (stride 32)
  float* bias   = ws + 18496;        // 64
  float* Mb     = ws + 18560;        // 64
  float* Zb     = ws + 18624;        // 64
  float* energ  = ws + 18688;        // 262144
  float* blk_m  = ws + 280832;       // 2048
  float* blk_Z  = ws + 282880;       // 2048
  float* blk_cx = ws + 284928;       // 524288  (total ~3.1 MiB)

  k_detect<<<1, 64, 0, stream>>>((const u16*)Ww, flag);
  k_prep<<<B_, 256, 0, stream>>>(qv, Ww, Lw, cw, cb, qW, kern, bias, flag);
  k_main<<<dim3(NCH_, B_ / 2), 256, 0, stream>>>(enc, mask, qW, kern, bias,
                                                 energ, blk_m, blk_Z, blk_cx, flag);
  k_combine<<<B_, 256, 0, stream>>>(blk_m, blk_Z, blk_cx, Mb, Zb, d_out, flag);
  k_attn<<<(B_ * T_) / 256, 256, 0, stream>>>(energ, Mb, Zb, d_out, flag);
}

// Round 4
// 405.643 us; speedup vs baseline: 1.0318x; 1.0312x over previous
//
#include <hip/hip_runtime.h>
#include <hip/hip_bf16.h>

#define B_    64
#define T_    4096
#define DIM_  256
#define NLOC_ 32
#define KS_   31
#define PAD_  15
#define CHUNK_ 128
#define NCH_  (T_ / CHUNK_)   // 32 chunks per batch
#define HALO_ (CHUNK_ + 2 * PAD_)

typedef unsigned short u16;
typedef unsigned int   u32;

__device__ __forceinline__ float bf2f(u16 u) {
  return __uint_as_float(((u32)u) << 16);
}
__device__ __forceinline__ u16 f2bf(float f) {
  u32 x = __float_as_uint(f);
  return (u16)((x + 0x7fffu + ((x >> 16) & 1u)) >> 16);   // RNE
}

template<bool F32>
__device__ __forceinline__ float ldv(const void* p, size_t i) {
  if constexpr (F32) return ((const float*)p)[i];
  else               return bf2f(((const u16*)p)[i]);
}
template<bool F32>
__device__ __forceinline__ void ld8(const void* p, size_t i, float ef[8]) {
  if constexpr (F32) {
    const float4* q = (const float4*)((const float*)p + i);
    float4 a = q[0], b = q[1];
    ef[0]=a.x; ef[1]=a.y; ef[2]=a.z; ef[3]=a.w;
    ef[4]=b.x; ef[5]=b.y; ef[6]=b.z; ef[7]=b.w;
  } else {
    uint4 c = *(const uint4*)((const u16*)p + i);
    ef[0]=__uint_as_float(c.x << 16); ef[1]=__uint_as_float(c.x & 0xffff0000u);
    ef[2]=__uint_as_float(c.y << 16); ef[3]=__uint_as_float(c.y & 0xffff0000u);
    ef[4]=__uint_as_float(c.z << 16); ef[5]=__uint_as_float(c.z & 0xffff0000u);
    ef[6]=__uint_as_float(c.w << 16); ef[7]=__uint_as_float(c.w & 0xffff0000u);
  }
}

// dtype census over first 4096 u16 of W_w, done by lanes 0..63 (wave 0).
// truly bf16 (N(0,1/256)): ~0 extremes; f32-as-bf16: ~35% extremes.
__device__ __forceinline__ int detect_census(const u16* __restrict__ w) {
  int tid = threadIdx.x;   // caller guarantees tid < 64
  int cnt = 0;
  for (int i = tid; i < 4096; i += 64) {
    float a = fabsf(bf2f(w[i]));
    if (!(a < 64.f) || (a > 0.f && a < 1e-20f)) cnt++;
  }
  #pragma unroll
  for (int o = 32; o >= 1; o >>= 1) cnt += __shfl_xor(cnt, o, 64);
  return (cnt > 200) ? 1 : 0;
}

// ---------------- Pass 0: self-detect + fold query into W / (L_w, conv) ----
template<bool F32>
__device__ __forceinline__ void prep_body(
    const void* qv, const void* Ww, const void* Lw, const void* cw,
    const void* cb, float* qW, float* kern, float* bias)
{
  const int b = blockIdx.x, tid = threadIdx.x;
  __shared__ float q_s[DIM_];
  __shared__ float qL_s[NLOC_];
  q_s[tid] = ldv<F32>(qv, b * DIM_ + tid);
  __syncthreads();
  float acc = 0.f;
  #pragma unroll 8
  for (int e = 0; e < DIM_; ++e) acc += q_s[e] * ldv<F32>(Ww, e * DIM_ + tid);
  qW[b * DIM_ + tid] = acc;
  if (tid < NLOC_) {
    float a = 0.f;
    #pragma unroll 8
    for (int e = 0; e < DIM_; ++e) a += q_s[e] * ldv<F32>(Lw, e * NLOC_ + tid);
    qL_s[tid] = a;
  }
  __syncthreads();
  if (tid < KS_) {
    float a = 0.f;
    #pragma unroll
    for (int c = 0; c < NLOC_; ++c) a += ldv<F32>(cw, c * KS_ + tid) * qL_s[c];
    kern[b * 32 + tid] = a;
  } else if (tid == KS_) {
    float a = 0.f;
    #pragma unroll
    for (int c = 0; c < NLOC_; ++c) a += ldv<F32>(cb, c) * qL_s[c];
    bias[b] = a;
  }
}

__global__ __launch_bounds__(256) void k_prep(
    const void* qv, const void* Ww, const void* Lw, const void* cw,
    const void* cb, float* qW, float* kern, float* bias, int* flag)
{
  __shared__ int f_s;
  if (threadIdx.x < 64) {
    int f = detect_census((const u16*)Ww);
    if (threadIdx.x == 0) {
      f_s = f;
      if (blockIdx.x == 0) *flag = f;   // publish for k_main / k_fin
    }
  }
  __syncthreads();
  if (f_s) prep_body<true >(qv, Ww, Lw, cw, cb, qW, kern, bias);
  else     prep_body<false>(qv, Ww, Lw, cw, cb, qW, kern, bias);
}

// ---------------- Pass 1: fused energies + online-softmax partials ----------
// grid (NCH_, B_/2). Wave halves own adjacent batches (b0, b0+1) of the SAME
// t -> each wave load is one contiguous 1 KiB segment.
template<bool F32>
__device__ __forceinline__ void main_body(
    const void* enc, const void* mask,
    const float* qW, const float* kern, const float* bias,
    float* energies, float* blk_m, float* blk_Z, float* blk_ctx)
{
  const int ch = blockIdx.x, t0 = ch * CHUNK_;
  const int b0 = blockIdx.y * 2;
  const int tid = threadIdx.x;
  const int wave = tid >> 6, lane = tid & 63, half = lane >> 5, hl = lane & 31;
  const int b = b0 + half;
  const int halfid = wave * 2 + half;   // 0..7; parity = b offset

  __shared__ float mask_s[2][HALO_];
  __shared__ float kern_s[2][32];
  __shared__ float loc_s[2][CHUNK_];
  __shared__ float e_s[2][CHUNK_];
  __shared__ float pm[8], pZ[8];
  __shared__ float pctx[8][DIM_];

  for (int i = tid; i < 2 * HALO_; i += 256) {
    int bo = i / HALO_, ii = i - bo * HALO_;
    int g = t0 - PAD_ + ii;
    mask_s[bo][ii] = (g >= 0 && g < T_) ? ldv<F32>(mask, (size_t)(b0 + bo) * T_ + g) : 0.f;
  }
  if (tid < 64) {
    int bo = tid >> 5, k = tid & 31;
    kern_s[bo][k] = (k < KS_) ? kern[(b0 + bo) * 32 + k] : bias[b0 + bo];
  }

  float wq[8];
  {
    const float4* q4 = (const float4*)(qW + (size_t)b * DIM_ + 8 * hl);
    float4 a = q4[0], c = q4[1];
    wq[0]=a.x; wq[1]=a.y; wq[2]=a.z; wq[3]=a.w;
    wq[4]=c.x; wq[5]=c.y; wq[6]=c.z; wq[7]=c.w;
  }
  __syncthreads();

  {
    int bo = tid >> 7, i = tid & (CHUNK_ - 1);
    float a = kern_s[bo][31];
    #pragma unroll
    for (int k = 0; k < KS_; ++k) a += mask_s[bo][i + k] * kern_s[bo][k];
    loc_s[bo][i] = a;
  }
  __syncthreads();

  const int tA = t0 + wave * 32;
  float m = -INFINITY, Z = 0.f;
  float ctx[8];
  #pragma unroll
  for (int q = 0; q < 8; ++q) ctx[q] = 0.f;

  const size_t STEP = (size_t)B_ * DIM_;
  const size_t base = ((size_t)tA * B_ + b) * DIM_ + 8 * hl;
  const int NIT = 32;

  auto process = [&](const float ef[8], int j) {
    float p = wq[0]*ef[0] + wq[1]*ef[1] + wq[2]*ef[2] + wq[3]*ef[3]
            + wq[4]*ef[4] + wq[5]*ef[5] + wq[6]*ef[6] + wq[7]*ef[7];
    #pragma unroll
    for (int o = 16; o >= 1; o >>= 1) p += __shfl_xor(p, o, 64);
    const int tloc = wave * 32 + j;
    float e = p + loc_s[half][tloc];
    if (hl == 0) e_s[half][tloc] = e;
    float mn = fmaxf(m, e);
    float sc = __expf(m - mn);
    float w  = __expf(e - mn);
    Z = Z * sc + w;
    #pragma unroll
    for (int q = 0; q < 8; ++q) ctx[q] = ctx[q] * sc + w * ef[q];
    m = mn;
  };

  float efA[8], efB[8];
  ld8<F32>(enc, base, efA);
  for (int j = 0; j < NIT; j += 2) {
    ld8<F32>(enc, base + (size_t)(j + 1) * STEP, efB);
    process(efA, j);
    if (j + 2 < NIT) ld8<F32>(enc, base + (size_t)(j + 2) * STEP, efA);
    process(efB, j + 1);
  }

  if (hl == 0) { pm[halfid] = m; pZ[halfid] = Z; }
  #pragma unroll
  for (int q = 0; q < 8; ++q) pctx[halfid][8 * hl + q] = ctx[q];
  __syncthreads();

  {
    int bo = tid >> 7, i = tid & (CHUNK_ - 1);
    energies[(size_t)(b0 + bo) * T_ + t0 + i] = e_s[bo][i];
  }

  #pragma unroll
  for (int bo = 0; bo < 2; ++bo) {
    float M = pm[bo];
    #pragma unroll
    for (int wv = 1; wv < 4; ++wv) M = fmaxf(M, pm[bo + 2 * wv]);
    float cx = 0.f;
    #pragma unroll
    for (int wv = 0; wv < 4; ++wv)
      cx += __expf(pm[bo + 2 * wv] - M) * pctx[bo + 2 * wv][tid];
    blk_ctx[((size_t)(b0 + bo) * NCH_ + ch) * DIM_ + tid] = cx;
    if (tid == 0) {
      float Zc = 0.f;
      #pragma unroll
      for (int wv = 0; wv < 4; ++wv) Zc += __expf(pm[bo + 2 * wv] - M) * pZ[bo + 2 * wv];
      blk_m[(b0 + bo) * NCH_ + ch] = M;
      blk_Z[(b0 + bo) * NCH_ + ch] = Zc;
    }
  }
}

__global__ __launch_bounds__(256) void k_main(
    const void* enc, const void* mask,
    const float* qW, const float* kern, const float* bias,
    float* energies, float* blk_m, float* blk_Z, float* blk_ctx,
    const int* flag)
{
  if (*flag) main_body<true >(enc, mask, qW, kern, bias, energies, blk_m, blk_Z, blk_ctx);
  else       main_body<false>(enc, mask, qW, kern, bias, energies, blk_m, blk_Z, blk_ctx);
}

// ---------------- Pass 2 (fused): finalize attn + context -------------------
// grid 1024: bid -> (b = bid>>4, seg = bid&15), t in [seg*256, +256).
// Every block rebuilds (M, Z) from the 32 chunk partials (L2-hot).
// seg==0 blocks additionally emit the context row for their b.
__global__ __launch_bounds__(256) void k_fin(
    const float* __restrict__ energies, const float* __restrict__ blk_m,
    const float* __restrict__ blk_Z, const float* __restrict__ blk_ctx,
    void* __restrict__ out, const int* __restrict__ flag)
{
  const int bid = blockIdx.x;
  const int b = bid >> 4, seg = bid & 15;
  const int tid = threadIdx.x;
  const int f32 = *flag;

  __shared__ float sm[NCH_], sZ[NCH_];
  if (tid < NCH_) { sm[tid] = blk_m[b * NCH_ + tid]; sZ[tid] = blk_Z[b * NCH_ + tid]; }
  __syncthreads();
  float M = sm[0];
  #pragma unroll
  for (int i = 1; i < NCH_; ++i) M = fmaxf(M, sm[i]);
  float Zg = 0.f;
  #pragma unroll
  for (int i = 0; i < NCH_; ++i) Zg += __expf(sm[i] - M) * sZ[i];

  // attn for 256 t's
  const int t = seg * 256 + tid;
  float a = __expf(energies[(size_t)b * T_ + t] - M) / Zg;
  const size_t attn_off = (size_t)B_ * DIM_ + (size_t)b * T_ + t;
  if (f32) ((float*)out)[attn_off] = a;
  else     ((u16*)out)[attn_off]   = f2bf(a);

  // context (one block per b)
  if (seg == 0) {
    float cx = 0.f;
    for (int i = 0; i < NCH_; ++i)
      cx += __expf(sm[i] - M) * blk_ctx[((size_t)b * NCH_ + i) * DIM_ + tid];
    float v = cx / Zg;
    if (f32) ((float*)out)[b * DIM_ + tid] = v;
    else     ((u16*)out)[b * DIM_ + tid]   = f2bf(v);
  }
}

extern "C" void kernel_launch(void* const* d_in, const int* in_sizes, int n_in,
                              void* d_out, int out_size, void* d_ws, size_t ws_size,
                              hipStream_t stream) {
  const void* qv   = d_in[0];  // (1,64,256)
  const void* enc  = d_in[1];  // (4096,64,256)
  const void* mask = d_in[2];  // (64,4096,1)
  const void* Ww   = d_in[3];  // (256,256)
  const void* Lw   = d_in[4];  // (256,32)
  const void* cw   = d_in[5];  // (32,1,31)
  const void* cb   = d_in[6];  // (32,)

  float* ws     = (float*)d_ws;
  int*   flag   = (int*)ws;          // [0]
  float* qW     = ws + 64;           // 16384
  float* kern   = ws + 16448;        // 2048 (stride 32)
  float* bias   = ws + 18496;        // 64
  float* energ  = ws + 18688;        // 262144
  float* blk_m  = ws + 280832;       // 2048
  float* blk_Z  = ws + 282880;       // 2048
  float* blk_cx = ws + 284928;       // 524288  (total ~3.1 MiB)

  k_prep<<<B_, 256, 0, stream>>>(qv, Ww, Lw, cw, cb, qW, kern, bias, flag);
  k_main<<<dim3(NCH_, B_ / 2), 256, 0, stream>>>(enc, mask, qW, kern, bias,
                                                 energ, blk_m, blk_Z, blk_cx, flag);
  k_fin<<<1024, 256, 0, stream>>>(energ, blk_m, blk_Z, blk_cx, d_out, flag);
}